// Round 2
// baseline (9342.844 us; speedup 1.0000x reference)
//
#include <hip/hip_runtime.h>
#include <math.h>

static constexpr int N = 8192;
static constexpr int M = 256;

__device__ __forceinline__ void sm_combine(float& m, float& s, float m2, float s2) {
  float nm = fmaxf(m, m2);
  s = s * __expf(m - nm) + s2 * __expf(m2 - nm);
  m = nm;
}

// ---------------------------------------------------------------------------
// C[M_ x N_] = A[M_ x K] @ B[N_ x K]^T  (row-major, contract over K). For Ap.
// ---------------------------------------------------------------------------
__global__ __launch_bounds__(256) void gemm_nt(const float* __restrict__ A, int lda,
                                               const float* __restrict__ B, int ldb,
                                               float* __restrict__ C, int ldc, int K) {
  __shared__ float As[32 * 68];
  __shared__ float Bs[32 * 68];
  const int tid = threadIdx.x;
  const int ty = tid >> 4, tx = tid & 15;
  const int row0 = blockIdx.x * 64, col0 = blockIdx.y * 64;
  float acc[4][4] = {};

  for (int k0 = 0; k0 < K; k0 += 32) {
#pragma unroll
    for (int l = 0; l < 8; ++l) {
      int idx = tid + l * 256;
      int r = idx >> 5, c = idx & 31;
      As[c * 68 + r] = A[(size_t)(row0 + r) * lda + k0 + c];
      Bs[c * 68 + r] = B[(size_t)(col0 + r) * ldb + k0 + c];
    }
    __syncthreads();
#pragma unroll
    for (int kk = 0; kk < 32; ++kk) {
      float4 a = *(const float4*)(As + kk * 68 + ty * 4);
      float4 b = *(const float4*)(Bs + kk * 68 + tx * 4);
      float av[4] = {a.x, a.y, a.z, a.w}, bv[4] = {b.x, b.y, b.z, b.w};
#pragma unroll
      for (int r = 0; r < 4; ++r)
#pragma unroll
        for (int c = 0; c < 4; ++c) acc[r][c] = fmaf(av[r], bv[c], acc[r][c]);
    }
    __syncthreads();
  }
#pragma unroll
  for (int r = 0; r < 4; ++r)
#pragma unroll
    for (int c = 0; c < 4; ++c)
      C[(size_t)(row0 + ty * 4 + r) * ldc + col0 + tx * 4 + c] = acc[r][c];
}

// ---------------------------------------------------------------------------
// Pass 1: per (64-row panel p, 4096-col half h): compute corr tiles, exact
// row stats (reduced at end), per-panel column partials.
// thread map: ty = tid&15 (rows ty*4+r), tx = tid>>4 (cols tx*4+cc)
// ---------------------------------------------------------------------------
__global__ __launch_bounds__(256) void stats_pass(
    const float* __restrict__ Ap, const float* __restrict__ video,
    float* __restrict__ rpm, float* __restrict__ rps,
    float* __restrict__ cpm, float* __restrict__ cps) {
  __shared__ float As[32 * 68];
  __shared__ float Bs[32 * 68];
  const int tid = threadIdx.x;
  const int ty = tid & 15, tx = tid >> 4;
  const int p = blockIdx.x, h = blockIdx.y;
  const float* Abase = Ap + (size_t)p * 64 * M;

  float rm[4], rs[4];
#pragma unroll
  for (int r = 0; r < 4; ++r) { rm[r] = -INFINITY; rs[r] = 0.f; }

#pragma unroll 1
  for (int j0 = h * 4096; j0 < h * 4096 + 4096; j0 += 64) {
    const float* Bbase = video + (size_t)j0 * M;
    float c[4][4] = {};
#pragma unroll 1
    for (int k0 = 0; k0 < M; k0 += 32) {
#pragma unroll
      for (int l = 0; l < 8; ++l) {
        int idx = tid + l * 256;
        int rr = idx >> 5, kk = idx & 31;
        As[kk * 68 + rr] = Abase[(size_t)rr * M + k0 + kk];
        Bs[kk * 68 + rr] = Bbase[(size_t)rr * M + k0 + kk];
      }
      __syncthreads();
#pragma unroll
      for (int kk = 0; kk < 32; ++kk) {
        float4 a = *(const float4*)(As + kk * 68 + ty * 4);
        float4 b = *(const float4*)(Bs + kk * 68 + tx * 4);
        float av[4] = {a.x, a.y, a.z, a.w}, bv[4] = {b.x, b.y, b.z, b.w};
#pragma unroll
        for (int r = 0; r < 4; ++r)
#pragma unroll
          for (int cc = 0; cc < 4; ++cc) c[r][cc] = fmaf(av[r], bv[cc], c[r][cc]);
      }
      __syncthreads();
    }
    // row stats (online)
#pragma unroll
    for (int r = 0; r < 4; ++r) {
      float tm = fmaxf(fmaxf(c[r][0], c[r][1]), fmaxf(c[r][2], c[r][3]));
      float nm = fmaxf(rm[r], tm);
      float add = __expf(c[r][0] - nm) + __expf(c[r][1] - nm) +
                  __expf(c[r][2] - nm) + __expf(c[r][3] - nm);
      rs[r] = rs[r] * __expf(rm[r] - nm) + add;
      rm[r] = nm;
    }
    // column partials: reduce over ty (lane bits 0..3), lane ty==0 writes
#pragma unroll
    for (int cc = 0; cc < 4; ++cc) {
      float cm = fmaxf(fmaxf(c[0][cc], c[1][cc]), fmaxf(c[2][cc], c[3][cc]));
      float cs = __expf(c[0][cc] - cm) + __expf(c[1][cc] - cm) +
                 __expf(c[2][cc] - cm) + __expf(c[3][cc] - cm);
#pragma unroll
      for (int k = 1; k < 16; k <<= 1) {
        float m2 = __shfl_xor(cm, k);
        float s2 = __shfl_xor(cs, k);
        sm_combine(cm, cs, m2, s2);
      }
      if (ty == 0) {
        cpm[(size_t)p * N + j0 + tx * 4 + cc] = cm;
        cps[(size_t)p * N + j0 + tx * 4 + cc] = cs;
      }
    }
  }
  // final row reduce over tx via LDS
  __syncthreads();
#pragma unroll
  for (int r = 0; r < 4; ++r) {
    As[tx * 64 + ty * 4 + r] = rm[r];
    Bs[tx * 64 + ty * 4 + r] = rs[r];
  }
  __syncthreads();
  if (tid < 64) {
    float m = As[tid], s = Bs[tid];
#pragma unroll 1
    for (int t = 1; t < 16; ++t) sm_combine(m, s, As[t * 64 + tid], Bs[t * 64 + tid]);
    rpm[(size_t)h * N + p * 64 + tid] = m;
    rps[(size_t)h * N + p * 64 + tid] = s;
  }
}

__global__ __launch_bounds__(256) void row_final(const float* __restrict__ rpm,
                                                 const float* __restrict__ rps,
                                                 float* __restrict__ rmax,
                                                 float* __restrict__ rinv) {
  int r = blockIdx.x * 256 + threadIdx.x;
  float m = rpm[r], s = rps[r];
  sm_combine(m, s, rpm[N + r], rps[N + r]);
  rmax[r] = m;
  rinv[r] = 1.f / s;
}

__global__ __launch_bounds__(256) void col_final(const float* __restrict__ cpm,
                                                 const float* __restrict__ cps,
                                                 float* __restrict__ cmax,
                                                 float* __restrict__ cinv) {
  int c = blockIdx.x * 256 + threadIdx.x;
  float m = cpm[c], s = cps[c];
#pragma unroll 1
  for (int p = 1; p < 128; ++p)
    sm_combine(m, s, cpm[(size_t)p * N + c], cps[(size_t)p * N + c]);
  cmax[c] = m;
  cinv[c] = 1.f / s;
}

// ---------------------------------------------------------------------------
// out[:, M:2M] = tanh(w_audio @ audio + audio); w_audio[i,j]=exp(corr[i,j]-cmax[j])*cinv[j]
// 32-row i-block, j-tiles of 64. corr phase: c[ia=ty*2+r][jb=tx*4+cc].
// accum phase: i = ty*2+r, m = q*64+tx*4+cc.
// ---------------------------------------------------------------------------
__global__ __launch_bounds__(256) void out_audio_f(
    const float* __restrict__ Ap, const float* __restrict__ video,
    const float* __restrict__ audio, const float* __restrict__ cmax,
    const float* __restrict__ cinv, float* __restrict__ out) {
  __shared__ float S[6528];
  float* As = S;           // corr: [kk][ia], stride 34 (32x34 = 1088)
  float* Bs = S + 1088;    // corr: [kk][jb], stride 68 (32x68 = 2176)
  float* Ws = S;           // weights: [jb][ia], stride 34 (64x34 = 2176)
  float* Auds = S + 2176;  // accum: [jj][mm], stride 68 (64x68 = 4352)
  const int tid = threadIdx.x;
  const int ty = tid & 15, tx = tid >> 4;
  const int i0 = blockIdx.x * 32;

  float acc[2][16] = {};

#pragma unroll 1
  for (int j0 = 0; j0 < N; j0 += 64) {
    float c[2][4] = {};
#pragma unroll 1
    for (int k0 = 0; k0 < M; k0 += 32) {
#pragma unroll
      for (int l = 0; l < 4; ++l) {
        int idx = tid + l * 256;
        int ia = idx >> 5, kk = idx & 31;
        As[kk * 34 + ia] = Ap[(size_t)(i0 + ia) * M + k0 + kk];
      }
#pragma unroll
      for (int l = 0; l < 8; ++l) {
        int idx = tid + l * 256;
        int jb = idx >> 5, kk = idx & 31;
        Bs[kk * 68 + jb] = video[(size_t)(j0 + jb) * M + k0 + kk];
      }
      __syncthreads();
#pragma unroll
      for (int kk = 0; kk < 32; ++kk) {
        float2 a = *(const float2*)(As + kk * 34 + ty * 2);
        float4 b = *(const float4*)(Bs + kk * 68 + tx * 4);
        float av[2] = {a.x, a.y}, bv[4] = {b.x, b.y, b.z, b.w};
#pragma unroll
        for (int r = 0; r < 2; ++r)
#pragma unroll
          for (int cc = 0; cc < 4; ++cc) c[r][cc] = fmaf(av[r], bv[cc], c[r][cc]);
      }
      __syncthreads();
    }
    // weights -> Ws[jb][ia]  (overwrites dead As/Bs)
#pragma unroll
    for (int cc = 0; cc < 4; ++cc) {
      int j = j0 + tx * 4 + cc;
      float cm = cmax[j], ci = cinv[j];
#pragma unroll
      for (int r = 0; r < 2; ++r)
        Ws[(tx * 4 + cc) * 34 + ty * 2 + r] = __expf(c[r][cc] - cm) * ci;
    }
    __syncthreads();
#pragma unroll 1
    for (int q = 0; q < 4; ++q) {
#pragma unroll
      for (int l = 0; l < 16; ++l) {
        int idx = tid + l * 256;
        int jj = idx >> 6, mm = idx & 63;
        Auds[jj * 68 + mm] = audio[(size_t)(j0 + jj) * M + q * 64 + mm];
      }
      __syncthreads();
#pragma unroll
      for (int jj = 0; jj < 64; ++jj) {
        float2 w = *(const float2*)(Ws + jj * 34 + ty * 2);
        float4 v = *(const float4*)(Auds + jj * 68 + tx * 4);
        float wv[2] = {w.x, w.y}, vv[4] = {v.x, v.y, v.z, v.w};
#pragma unroll
        for (int r = 0; r < 2; ++r)
#pragma unroll
          for (int cc = 0; cc < 4; ++cc)
            acc[r][q * 4 + cc] = fmaf(wv[r], vv[cc], acc[r][q * 4 + cc]);
      }
      __syncthreads();
    }
  }
#pragma unroll
  for (int r = 0; r < 2; ++r) {
    int i = i0 + ty * 2 + r;
#pragma unroll
    for (int q = 0; q < 4; ++q)
#pragma unroll
      for (int cc = 0; cc < 4; ++cc) {
        int m = q * 64 + tx * 4 + cc;
        out[(size_t)i * (2 * M) + M + m] = tanhf(acc[r][q * 4 + cc] + audio[(size_t)i * M + m]);
      }
  }
}

// ---------------------------------------------------------------------------
// out[:, 0:M] = tanh(softmax(corr,1)^T @ video + video)
// corr phase computes corr[j,i] tile: c[ja=ty*4+r][ib=tx*2+cc], j=j0+ja.
// weights P[j,i] = exp(corr[j,i]-rmax[j])*rinv[j] -> Ws[ja][ib].
// accum phase identical to out_audio_f with source=video.
// ---------------------------------------------------------------------------
__global__ __launch_bounds__(256) void out_video_f(
    const float* __restrict__ Ap, const float* __restrict__ video,
    const float* __restrict__ rmax, const float* __restrict__ rinv,
    float* __restrict__ out) {
  __shared__ float S[6528];
  float* As = S;           // corr: [kk][ja], stride 68 (32x68 = 2176)
  float* Bs = S + 2176;    // corr: [kk][ib], stride 34 (32x34 = 1088)
  float* Ws = S;           // weights: [ja][ib], stride 34 (64x34 = 2176)
  float* Vids = S + 2176;  // accum: [jj][mm], stride 68 (64x68 = 4352)
  const int tid = threadIdx.x;
  const int ty = tid & 15, tx = tid >> 4;
  const int i0 = blockIdx.x * 32;

  float acc[2][16] = {};

#pragma unroll 1
  for (int j0 = 0; j0 < N; j0 += 64) {
    float c[4][2] = {};
#pragma unroll 1
    for (int k0 = 0; k0 < M; k0 += 32) {
#pragma unroll
      for (int l = 0; l < 8; ++l) {
        int idx = tid + l * 256;
        int ja = idx >> 5, kk = idx & 31;
        As[kk * 68 + ja] = Ap[(size_t)(j0 + ja) * M + k0 + kk];
      }
#pragma unroll
      for (int l = 0; l < 4; ++l) {
        int idx = tid + l * 256;
        int ib = idx >> 5, kk = idx & 31;
        Bs[kk * 34 + ib] = video[(size_t)(i0 + ib) * M + k0 + kk];
      }
      __syncthreads();
#pragma unroll
      for (int kk = 0; kk < 32; ++kk) {
        float4 a = *(const float4*)(As + kk * 68 + ty * 4);
        float2 b = *(const float2*)(Bs + kk * 34 + tx * 2);
        float av[4] = {a.x, a.y, a.z, a.w}, bv[2] = {b.x, b.y};
#pragma unroll
        for (int r = 0; r < 4; ++r)
#pragma unroll
          for (int cc = 0; cc < 2; ++cc) c[r][cc] = fmaf(av[r], bv[cc], c[r][cc]);
      }
      __syncthreads();
    }
    // weights -> Ws[ja][ib]
#pragma unroll
    for (int r = 0; r < 4; ++r) {
      int j = j0 + ty * 4 + r;
      float rmx = rmax[j], ri = rinv[j];
#pragma unroll
      for (int cc = 0; cc < 2; ++cc)
        Ws[(ty * 4 + r) * 34 + tx * 2 + cc] = __expf(c[r][cc] - rmx) * ri;
    }
    __syncthreads();
#pragma unroll 1
    for (int q = 0; q < 4; ++q) {
#pragma unroll
      for (int l = 0; l < 16; ++l) {
        int idx = tid + l * 256;
        int jj = idx >> 6, mm = idx & 63;
        Vids[jj * 68 + mm] = video[(size_t)(j0 + jj) * M + q * 64 + mm];
      }
      __syncthreads();
#pragma unroll
      for (int jj = 0; jj < 64; ++jj) {
        float2 w = *(const float2*)(Ws + jj * 34 + ty * 2);
        float4 v = *(const float4*)(Vids + jj * 68 + tx * 4);
        float wv[2] = {w.x, w.y}, vv[4] = {v.x, v.y, v.z, v.w};
#pragma unroll
        for (int r = 0; r < 2; ++r)
#pragma unroll
          for (int cc = 0; cc < 4; ++cc)
            acc[r][q * 4 + cc] = fmaf(wv[r], vv[cc], acc[r][q * 4 + cc]);
      }
      __syncthreads();
    }
  }
#pragma unroll
  for (int r = 0; r < 2; ++r) {
    int i = i0 + ty * 2 + r;
#pragma unroll
    for (int q = 0; q < 4; ++q)
#pragma unroll
      for (int cc = 0; cc < 4; ++cc) {
        int m = q * 64 + tx * 4 + cc;
        out[(size_t)i * (2 * M) + m] = tanhf(acc[r][q * 4 + cc] + video[(size_t)i * M + m]);
      }
  }
}

// ---------------------------------------------------------------------------
extern "C" void kernel_launch(void* const* d_in, const int* in_sizes, int n_in,
                              void* d_out, int out_size, void* d_ws, size_t ws_size,
                              hipStream_t stream) {
  const float* audio = (const float*)d_in[0];
  const float* video = (const float*)d_in[1];
  const float* W = (const float*)d_in[2];
  float* out = (float*)d_out;
  float* ws = (float*)d_ws;

  // workspace layout (floats): total ~17.04 MB
  float* Ap = ws;                          // N*M
  float* rpm = Ap + (size_t)N * M;         // 2*N
  float* rps = rpm + 2 * (size_t)N;        // 2*N
  float* cpm = rps + 2 * (size_t)N;        // 128*N
  float* cps = cpm + 128 * (size_t)N;      // 128*N
  float* rmax = cps + 128 * (size_t)N;     // N
  float* rinv = rmax + N;                  // N
  float* cmax = rinv + N;                  // N
  float* cinv = cmax + N;                  // N
  const size_t needFloats =
      (size_t)N * M + 4 * (size_t)N + 256 * (size_t)N + 4 * (size_t)N;
  if (ws_size < needFloats * sizeof(float)) return;

  // 1. Ap = audio @ W^T  [N, M]
  gemm_nt<<<dim3(N / 64, M / 64), 256, 0, stream>>>(audio, M, W, M, Ap, M, M);
  // 2. softmax stats
  stats_pass<<<dim3(128, 2), 256, 0, stream>>>(Ap, video, rpm, rps, cpm, cps);
  row_final<<<N / 256, 256, 0, stream>>>(rpm, rps, rmax, rinv);
  col_final<<<N / 256, 256, 0, stream>>>(cpm, cps, cmax, cinv);
  // 3. outputs (corr recomputed per tile, fused softmax + tanh epilogue)
  out_video_f<<<N / 32, 256, 0, stream>>>(Ap, video, rmax, rinv, out);
  out_audio_f<<<N / 32, 256, 0, stream>>>(Ap, video, audio, cmax, cinv, out);
}

// Round 3
// 1883.786 us; speedup vs baseline: 4.9596x; 4.9596x over previous
//
#include <hip/hip_runtime.h>
#include <math.h>

static constexpr int N = 8192;
static constexpr int M = 256;
static constexpr float SHIFT = 96.0f;

typedef __attribute__((ext_vector_type(8))) short bf16x8;
typedef __attribute__((ext_vector_type(4))) float f32x4;

__device__ __forceinline__ unsigned short f2bf(float x) {
  unsigned int u = __builtin_bit_cast(unsigned int, x);
  u += 0x7fffu + ((u >> 16) & 1u);
  return (unsigned short)(u >> 16);
}
__device__ __forceinline__ float bf2f(unsigned short h) {
  unsigned int u = ((unsigned int)h) << 16;
  return __builtin_bit_cast(float, u);
}
__device__ __forceinline__ f32x4 mfma16(bf16x8 a, bf16x8 b, f32x4 c) {
  return __builtin_amdgcn_mfma_f32_16x16x32_bf16(a, b, c, 0, 0, 0);
}
__device__ __forceinline__ bf16x8 ld8(const unsigned short* p) {
  return *reinterpret_cast<const bf16x8*>(p);
}

// ---------------------------------------------------------------------------
__global__ void zero_f32(float* __restrict__ p, int n4) {
  int i = blockIdx.x * 256 + threadIdx.x;
  if (i < n4) reinterpret_cast<float4*>(p)[i] = float4{0.f, 0.f, 0.f, 0.f};
}

// ---------------------------------------------------------------------------
// Ap = audio @ W^T (fp32 VALU, small: 0.54 G-FMA), writes bf16 hi/lo.
// ---------------------------------------------------------------------------
__global__ __launch_bounds__(256) void gemm_ap(const float* __restrict__ A,
                                               const float* __restrict__ B,
                                               unsigned short* __restrict__ Ch,
                                               unsigned short* __restrict__ Cl) {
  __shared__ float As[32 * 68];
  __shared__ float Bs[32 * 68];
  const int tid = threadIdx.x;
  const int ty = tid >> 4, tx = tid & 15;
  const int row0 = blockIdx.x * 64, col0 = blockIdx.y * 64;
  float acc[4][4] = {};
  for (int k0 = 0; k0 < M; k0 += 32) {
#pragma unroll
    for (int l = 0; l < 8; ++l) {
      int idx = tid + l * 256;
      int r = idx >> 5, c = idx & 31;
      As[c * 68 + r] = A[(size_t)(row0 + r) * M + k0 + c];
      Bs[c * 68 + r] = B[(size_t)(col0 + r) * M + k0 + c];
    }
    __syncthreads();
#pragma unroll
    for (int kk = 0; kk < 32; ++kk) {
      float4 a = *(const float4*)(As + kk * 68 + ty * 4);
      float4 b = *(const float4*)(Bs + kk * 68 + tx * 4);
      float av[4] = {a.x, a.y, a.z, a.w}, bv[4] = {b.x, b.y, b.z, b.w};
#pragma unroll
      for (int r = 0; r < 4; ++r)
#pragma unroll
        for (int c = 0; c < 4; ++c) acc[r][c] = fmaf(av[r], bv[c], acc[r][c]);
    }
    __syncthreads();
  }
#pragma unroll
  for (int r = 0; r < 4; ++r)
#pragma unroll
    for (int c = 0; c < 4; ++c) {
      float x = acc[r][c];
      unsigned short h = f2bf(x);
      size_t o = (size_t)(row0 + ty * 4 + r) * M + col0 + tx * 4 + c;
      Ch[o] = h;
      Cl[o] = f2bf(x - bf2f(h));
    }
}

// ---------------------------------------------------------------------------
// Tiled transpose + hi/lo split. rh/rl (row-major) optional.
// ---------------------------------------------------------------------------
__global__ __launch_bounds__(256) void trsplit(const float* __restrict__ src,
                                               unsigned short* rh, unsigned short* rl,
                                               unsigned short* __restrict__ th,
                                               unsigned short* __restrict__ tl) {
  __shared__ float T[64][65];
  const int i0 = blockIdx.x * 64, m0 = blockIdx.y * 64;
  const int tid = threadIdx.x;
#pragma unroll
  for (int l = 0; l < 16; ++l) {
    int idx = tid + l * 256;
    int r = idx >> 6, c = idx & 63;
    float x = src[(size_t)(i0 + r) * M + m0 + c];
    T[r][c] = x;
    if (rh != nullptr) {
      unsigned short h = f2bf(x);
      size_t o = (size_t)(i0 + r) * M + m0 + c;
      rh[o] = h;
      rl[o] = f2bf(x - bf2f(h));
    }
  }
  __syncthreads();
#pragma unroll
  for (int l = 0; l < 16; ++l) {
    int idx = tid + l * 256;
    int r = idx >> 6, c = idx & 63;  // r: m-local, c: i-local
    float x = T[c][r];
    unsigned short h = f2bf(x);
    size_t o = (size_t)(m0 + r) * N + i0 + c;
    th[o] = h;
    tl[o] = f2bf(x - bf2f(h));
  }
}

// ---------------------------------------------------------------------------
// Stats: per (i-panel 128, j-eighth 1024): corr tiles via bf16x3 MFMA,
// E = exp(corr - 96); additive row partial sums + col partial sums.
// ---------------------------------------------------------------------------
__global__ __launch_bounds__(512) void stats_mfma(
    const unsigned short* __restrict__ Aph, const unsigned short* __restrict__ Apl,
    const unsigned short* __restrict__ Vh, const unsigned short* __restrict__ Vl,
    float* __restrict__ rps, float* __restrict__ cps) {
  __shared__ unsigned short Vs[64 * 264];
  __shared__ float cred[8][64];
  const int tid = threadIdx.x;
  const int w = tid >> 6, l = tid & 63;
  const int lm = l & 15, lk = l >> 4;
  const int p = blockIdx.x, q = blockIdx.y;
  const int arow = p * 128 + w * 16 + lm;

  bf16x8 ah[8];
#pragma unroll
  for (int kk = 0; kk < 8; ++kk) ah[kk] = ld8(Aph + (size_t)arow * M + kk * 32 + lk * 8);
  const unsigned short* alp = Apl + (size_t)arow * M + lk * 8;

  float rsum[4] = {0.f, 0.f, 0.f, 0.f};

  for (int jt = 0; jt < 16; ++jt) {
    const int j0 = q * 1024 + jt * 64;
    __syncthreads();
#pragma unroll
    for (int s = 0; s < 4; ++s) {
      int slot = tid + s * 512;
      int r = slot >> 5, c = slot & 31;
      *(bf16x8*)(Vs + r * 264 + c * 8) = ld8(Vh + (size_t)(j0 + r) * M + c * 8);
    }
    __syncthreads();

    f32x4 acc[4];
#pragma unroll
    for (int js = 0; js < 4; ++js) acc[js] = f32x4{0.f, 0.f, 0.f, 0.f};
#pragma unroll
    for (int js = 0; js < 4; ++js) {
      const unsigned short* vsr = Vs + (js * 16 + lm) * 264 + lk * 8;
      const unsigned short* vlr = Vl + (size_t)(j0 + js * 16 + lm) * M + lk * 8;
#pragma unroll
      for (int kk = 0; kk < 8; ++kk) {
        bf16x8 bh = ld8(vsr + kk * 32);
        bf16x8 bl = ld8(vlr + kk * 32);
        bf16x8 al = ld8(alp + kk * 32);
        acc[js] = mfma16(ah[kk], bh, acc[js]);
        acc[js] = mfma16(ah[kk], bl, acc[js]);
        acc[js] = mfma16(al, bh, acc[js]);
      }
    }
#pragma unroll
    for (int js = 0; js < 4; ++js) {
      float e0 = __expf(acc[js][0] - SHIFT), e1 = __expf(acc[js][1] - SHIFT);
      float e2 = __expf(acc[js][2] - SHIFT), e3 = __expf(acc[js][3] - SHIFT);
      rsum[0] += e0; rsum[1] += e1; rsum[2] += e2; rsum[3] += e3;
      float c = e0 + e1 + e2 + e3;
      c += __shfl_xor(c, 16);
      c += __shfl_xor(c, 32);
      if (lk == 0) cred[w][js * 16 + lm] = c;
    }
    __syncthreads();
    if (tid < 64) {
      float c = 0.f;
#pragma unroll
      for (int ww = 0; ww < 8; ++ww) c += cred[ww][tid];
      cps[(size_t)p * N + j0 + tid] = c;
    }
  }
#pragma unroll
  for (int r = 0; r < 4; ++r) {
    float s = rsum[r];
    s += __shfl_xor(s, 1);
    s += __shfl_xor(s, 2);
    s += __shfl_xor(s, 4);
    s += __shfl_xor(s, 8);
    if (lm == 0) rps[(size_t)q * N + p * 128 + w * 16 + lk * 4 + r] = s;
  }
}

__global__ void row_inv(const float* __restrict__ rps, float* __restrict__ rinv) {
  int i = blockIdx.x * 256 + threadIdx.x;
  float s = 0.f;
#pragma unroll
  for (int q = 0; q < 8; ++q) s += rps[(size_t)q * N + i];
  rinv[i] = 1.f / s;
}
__global__ void col_inv(const float* __restrict__ cps, float* __restrict__ cinv) {
  int j = blockIdx.x * 256 + threadIdx.x;
  float s = 0.f;
  for (int p = 0; p < 64; ++p) s += cps[(size_t)p * N + j];
  cinv[j] = 1.f / s;
}

// ---------------------------------------------------------------------------
// out_audio: d_audio[i,m] = sum_j E(corr[i,j])*cinv[j] * audio[j,m]
// corr tile: A = Ap[i-panel 64] (regs), B = V[j-tile 64] (LDS hi + global lo)
// ---------------------------------------------------------------------------
__global__ __launch_bounds__(512) void out_audio_m(
    const unsigned short* __restrict__ Aph, const unsigned short* __restrict__ Apl,
    const unsigned short* __restrict__ Vh, const unsigned short* __restrict__ Vl,
    const unsigned short* __restrict__ AuTh, const unsigned short* __restrict__ AuTl,
    const float* __restrict__ cinv, float* __restrict__ out) {
  __shared__ unsigned short Vs[64 * 264];
  __shared__ unsigned short Wh[64 * 72], Wl[64 * 72];
  const int tid = threadIdx.x;
  const int w = tid >> 6, l = tid & 63;
  const int lm = l & 15, lk = l >> 4;
  const int i0 = blockIdx.x * 64;
  const int jh = blockIdx.y;  // j-quarter
  const int isub = w & 3, half = w >> 2;

  const int arow = i0 + isub * 16 + lm;
  bf16x8 ah[8];
#pragma unroll
  for (int kk = 0; kk < 8; ++kk) ah[kk] = ld8(Aph + (size_t)arow * M + kk * 32 + lk * 8);
  const unsigned short* alp = Apl + (size_t)arow * M + lk * 8;

  f32x4 dacc[8];
#pragma unroll
  for (int ms = 0; ms < 8; ++ms) dacc[ms] = f32x4{0.f, 0.f, 0.f, 0.f};
  const int m0 = half * 128;

  for (int jt = 0; jt < 32; ++jt) {
    const int j0 = jh * 2048 + jt * 64;
    __syncthreads();
#pragma unroll
    for (int s = 0; s < 4; ++s) {
      int slot = tid + s * 512;
      int r = slot >> 5, c = slot & 31;
      *(bf16x8*)(Vs + r * 264 + c * 8) = ld8(Vh + (size_t)(j0 + r) * M + c * 8);
    }
    __syncthreads();

    f32x4 cacc[2];
    cacc[0] = f32x4{0.f, 0.f, 0.f, 0.f};
    cacc[1] = f32x4{0.f, 0.f, 0.f, 0.f};
#pragma unroll
    for (int js2 = 0; js2 < 2; ++js2) {
      int js = half * 2 + js2;
      const unsigned short* vsr = Vs + (js * 16 + lm) * 264 + lk * 8;
      const unsigned short* vlr = Vl + (size_t)(j0 + js * 16 + lm) * M + lk * 8;
#pragma unroll
      for (int kk = 0; kk < 8; ++kk) {
        bf16x8 bh = ld8(vsr + kk * 32);
        bf16x8 bl = ld8(vlr + kk * 32);
        bf16x8 al = ld8(alp + kk * 32);
        cacc[js2] = mfma16(ah[kk], bh, cacc[js2]);
        cacc[js2] = mfma16(ah[kk], bl, cacc[js2]);
        cacc[js2] = mfma16(al, bh, cacc[js2]);
      }
    }
    // weights -> LDS (lane holds rows isub*16+lk*4+r, col js*16+lm)
#pragma unroll
    for (int js2 = 0; js2 < 2; ++js2) {
      int js = half * 2 + js2;
      float ci = cinv[j0 + js * 16 + lm];
#pragma unroll
      for (int r = 0; r < 4; ++r) {
        float e = __expf(cacc[js2][r] - SHIFT) * ci;
        unsigned short h = f2bf(e);
        int irow = isub * 16 + lk * 4 + r;
        Wh[irow * 72 + js * 16 + lm] = h;
        Wl[irow * 72 + js * 16 + lm] = f2bf(e - bf2f(h));
      }
    }
    __syncthreads();
    // weighted: A = W rows (isub*16+lm), B = AuT
#pragma unroll
    for (int kk = 0; kk < 2; ++kk) {
      bf16x8 wh = ld8(Wh + (isub * 16 + lm) * 72 + kk * 32 + lk * 8);
      bf16x8 wl = ld8(Wl + (isub * 16 + lm) * 72 + kk * 32 + lk * 8);
#pragma unroll
      for (int ms = 0; ms < 8; ++ms) {
        size_t bo = (size_t)(m0 + ms * 16 + lm) * N + j0 + kk * 32 + lk * 8;
        bf16x8 vh8 = ld8(AuTh + bo);
        bf16x8 vl8 = ld8(AuTl + bo);
        dacc[ms] = mfma16(wh, vh8, dacc[ms]);
        dacc[ms] = mfma16(wh, vl8, dacc[ms]);
        dacc[ms] = mfma16(wl, vh8, dacc[ms]);
      }
    }
  }
#pragma unroll
  for (int ms = 0; ms < 8; ++ms)
#pragma unroll
    for (int r = 0; r < 4; ++r) {
      int i = i0 + isub * 16 + lk * 4 + r;
      int m = m0 + ms * 16 + lm;
      atomicAdd(out + (size_t)i * (2 * M) + M + m, dacc[ms][r]);
    }
}

// ---------------------------------------------------------------------------
// out_video: d_video[i,m] = sum_j E(corr[j,i])*rinv[j] * video[j,m]
// corr tile: A = Ap[j-tile] (global), B = video[i-panel] (LDS hi, once)
// ---------------------------------------------------------------------------
__global__ __launch_bounds__(512) void out_video_m(
    const unsigned short* __restrict__ Aph, const unsigned short* __restrict__ Apl,
    const unsigned short* __restrict__ Vh, const unsigned short* __restrict__ Vl,
    const unsigned short* __restrict__ ViTh, const unsigned short* __restrict__ ViTl,
    const float* __restrict__ rinv, float* __restrict__ out) {
  __shared__ unsigned short Vs[64 * 264];
  __shared__ unsigned short Wh[64 * 72], Wl[64 * 72];
  const int tid = threadIdx.x;
  const int w = tid >> 6, l = tid & 63;
  const int lm = l & 15, lk = l >> 4;
  const int i0 = blockIdx.x * 64;
  const int jh = blockIdx.y;
  const int jsub = w & 3, half = w >> 2;

  // stage video[i-panel] hi once
#pragma unroll
  for (int s = 0; s < 4; ++s) {
    int slot = tid + s * 512;
    int r = slot >> 5, c = slot & 31;
    *(bf16x8*)(Vs + r * 264 + c * 8) = ld8(Vh + (size_t)(i0 + r) * M + c * 8);
  }
  __syncthreads();

  f32x4 dacc[8];
#pragma unroll
  for (int ms = 0; ms < 8; ++ms) dacc[ms] = f32x4{0.f, 0.f, 0.f, 0.f};
  const int m0 = half * 128;

  for (int jt = 0; jt < 32; ++jt) {
    const int j0 = jh * 2048 + jt * 64;
    // corr: A = Ap rows j, B = video rows i (LDS hi + global lo)
    f32x4 cacc[2];
    cacc[0] = f32x4{0.f, 0.f, 0.f, 0.f};
    cacc[1] = f32x4{0.f, 0.f, 0.f, 0.f};
    const int jrow = j0 + jsub * 16 + lm;
    const unsigned short* aphr = Aph + (size_t)jrow * M + lk * 8;
    const unsigned short* aplr = Apl + (size_t)jrow * M + lk * 8;
#pragma unroll
    for (int kk = 0; kk < 8; ++kk) {
      bf16x8 ahf = ld8(aphr + kk * 32);
      bf16x8 alf = ld8(aplr + kk * 32);
#pragma unroll
      for (int is2 = 0; is2 < 2; ++is2) {
        int isub = half * 2 + is2;
        bf16x8 bh = ld8(Vs + (isub * 16 + lm) * 264 + kk * 32 + lk * 8);
        bf16x8 bl = ld8(Vl + (size_t)(i0 + isub * 16 + lm) * M + kk * 32 + lk * 8);
        cacc[is2] = mfma16(ahf, bh, cacc[is2]);
        cacc[is2] = mfma16(ahf, bl, cacc[is2]);
        cacc[is2] = mfma16(alf, bh, cacc[is2]);
      }
    }
    __syncthreads();  // prior weighted reads of W done
    // weights: lane holds D[j-local = jsub*16+lk*4+r][i-local = isub*16+lm]
    float rv[4];
#pragma unroll
    for (int r = 0; r < 4; ++r) rv[r] = rinv[j0 + jsub * 16 + lk * 4 + r];
#pragma unroll
    for (int is2 = 0; is2 < 2; ++is2) {
      int isub = half * 2 + is2;
#pragma unroll
      for (int r = 0; r < 4; ++r) {
        float e = __expf(cacc[is2][r] - SHIFT) * rv[r];
        unsigned short h = f2bf(e);
        int jl = jsub * 16 + lk * 4 + r;
        Wh[(isub * 16 + lm) * 72 + jl] = h;
        Wl[(isub * 16 + lm) * 72 + jl] = f2bf(e - bf2f(h));
      }
    }
    __syncthreads();
    // weighted: A = W rows (i-local jsub*16+lm!), reuse jsub as i-sub
#pragma unroll
    for (int kk = 0; kk < 2; ++kk) {
      bf16x8 wh = ld8(Wh + (jsub * 16 + lm) * 72 + kk * 32 + lk * 8);
      bf16x8 wl = ld8(Wl + (jsub * 16 + lm) * 72 + kk * 32 + lk * 8);
#pragma unroll
      for (int ms = 0; ms < 8; ++ms) {
        size_t bo = (size_t)(m0 + ms * 16 + lm) * N + j0 + kk * 32 + lk * 8;
        bf16x8 vh8 = ld8(ViTh + bo);
        bf16x8 vl8 = ld8(ViTl + bo);
        dacc[ms] = mfma16(wh, vh8, dacc[ms]);
        dacc[ms] = mfma16(wh, vl8, dacc[ms]);
        dacc[ms] = mfma16(wl, vh8, dacc[ms]);
      }
    }
  }
#pragma unroll
  for (int ms = 0; ms < 8; ++ms)
#pragma unroll
    for (int r = 0; r < 4; ++r) {
      int i = i0 + jsub * 16 + lk * 4 + r;
      int m = m0 + ms * 16 + lm;
      atomicAdd(out + (size_t)i * (2 * M) + m, dacc[ms][r]);
    }
}

// ---------------------------------------------------------------------------
__global__ void epilogue(float* __restrict__ out, const float* __restrict__ video,
                         const float* __restrict__ audio) {
  int idx = blockIdx.x * 256 + threadIdx.x;  // over N*512/4 float4s
  int i = idx >> 7;
  int c4 = idx & 127;
  float4 o = reinterpret_cast<float4*>(out)[(size_t)i * 128 + c4];
  const float* res = (c4 < 64) ? (video + (size_t)i * M + c4 * 4)
                               : (audio + (size_t)i * M + (c4 - 64) * 4);
  float4 rv = *reinterpret_cast<const float4*>(res);
  o.x = tanhf(o.x + rv.x);
  o.y = tanhf(o.y + rv.y);
  o.z = tanhf(o.z + rv.z);
  o.w = tanhf(o.w + rv.w);
  reinterpret_cast<float4*>(out)[(size_t)i * 128 + c4] = o;
}

// ---------------------------------------------------------------------------
extern "C" void kernel_launch(void* const* d_in, const int* in_sizes, int n_in,
                              void* d_out, int out_size, void* d_ws, size_t ws_size,
                              hipStream_t stream) {
  const float* audio = (const float*)d_in[0];
  const float* video = (const float*)d_in[1];
  const float* W = (const float*)d_in[2];
  float* out = (float*)d_out;

  // workspace layout (bytes)
  const size_t nBF = (size_t)N * M * sizeof(unsigned short);  // 4 MB
  char* base = (char*)d_ws;
  unsigned short* Aph = (unsigned short*)(base);
  unsigned short* Apl = (unsigned short*)(base + nBF);
  unsigned short* Vh = (unsigned short*)(base + 2 * nBF);
  unsigned short* Vl = (unsigned short*)(base + 3 * nBF);
  unsigned short* ViTh = (unsigned short*)(base + 4 * nBF);
  unsigned short* ViTl = (unsigned short*)(base + 5 * nBF);
  unsigned short* AuTh = (unsigned short*)(base + 6 * nBF);
  unsigned short* AuTl = (unsigned short*)(base + 7 * nBF);
  float* rps = (float*)(base + 8 * nBF);              // 8*N
  float* cps = rps + 8 * (size_t)N;                   // 64*N
  float* rinv = cps + 64 * (size_t)N;                 // N
  float* cinv = rinv + N;                             // N
  const size_t need = 8 * nBF + (74 * (size_t)N) * sizeof(float);
  if (ws_size < need) return;

  zero_f32<<<dim3((N * 2 * M / 4 + 255) / 256), 256, 0, stream>>>(out, N * 2 * M / 4);
  gemm_ap<<<dim3(N / 64, M / 64), 256, 0, stream>>>(audio, W, Aph, Apl);
  trsplit<<<dim3(N / 64, M / 64), 256, 0, stream>>>(video, Vh, Vl, ViTh, ViTl);
  trsplit<<<dim3(N / 64, M / 64), 256, 0, stream>>>(audio, nullptr, nullptr, AuTh, AuTl);
  stats_mfma<<<dim3(64, 8), 512, 0, stream>>>(Aph, Apl, Vh, Vl, rps, cps);
  row_inv<<<N / 256, 256, 0, stream>>>(rps, rinv);
  col_inv<<<N / 256, 256, 0, stream>>>(cps, cinv);
  out_audio_m<<<dim3(N / 64, 4), 512, 0, stream>>>(Aph, Apl, Vh, Vl, AuTh, AuTl, cinv, out);
  out_video_m<<<dim3(N / 64, 4), 512, 0, stream>>>(Aph, Apl, Vh, Vl, ViTh, ViTl, rinv, out);
  epilogue<<<dim3(N * 2 * M / 4 / 256), 256, 0, stream>>>(out, video, audio);
}

// Round 4
// 1883.426 us; speedup vs baseline: 4.9606x; 1.0002x over previous
//
#include <hip/hip_runtime.h>
#include <math.h>

static constexpr int N = 8192;
static constexpr int M = 256;
static constexpr float SHIFT = 96.0f;

typedef __attribute__((ext_vector_type(8))) short bf16x8;
typedef __attribute__((ext_vector_type(4))) float f32x4;

__device__ __forceinline__ unsigned short f2bf(float x) {
  unsigned int u = __builtin_bit_cast(unsigned int, x);
  u += 0x7fffu + ((u >> 16) & 1u);
  return (unsigned short)(u >> 16);
}
__device__ __forceinline__ float bf2f(unsigned short h) {
  unsigned int u = ((unsigned int)h) << 16;
  return __builtin_bit_cast(float, u);
}
__device__ __forceinline__ f32x4 mfma16(bf16x8 a, bf16x8 b, f32x4 c) {
  return __builtin_amdgcn_mfma_f32_16x16x32_bf16(a, b, c, 0, 0, 0);
}
__device__ __forceinline__ bf16x8 ld8(const unsigned short* p) {
  return *reinterpret_cast<const bf16x8*>(p);
}

// ---------------------------------------------------------------------------
__global__ void zero_f32(float* __restrict__ p, int n4) {
  int i = blockIdx.x * 256 + threadIdx.x;
  if (i < n4) reinterpret_cast<float4*>(p)[i] = float4{0.f, 0.f, 0.f, 0.f};
}

// ---------------------------------------------------------------------------
// Ap = audio @ W^T (fp32 VALU, small: 0.54 G-FMA), writes bf16 hi/lo.
// ---------------------------------------------------------------------------
__global__ __launch_bounds__(256) void gemm_ap(const float* __restrict__ A,
                                               const float* __restrict__ B,
                                               unsigned short* __restrict__ Ch,
                                               unsigned short* __restrict__ Cl) {
  __shared__ float As[32 * 68];
  __shared__ float Bs[32 * 68];
  const int tid = threadIdx.x;
  const int ty = tid >> 4, tx = tid & 15;
  const int row0 = blockIdx.x * 64, col0 = blockIdx.y * 64;
  float acc[4][4] = {};
  for (int k0 = 0; k0 < M; k0 += 32) {
#pragma unroll
    for (int l = 0; l < 8; ++l) {
      int idx = tid + l * 256;
      int r = idx >> 5, c = idx & 31;
      As[c * 68 + r] = A[(size_t)(row0 + r) * M + k0 + c];
      Bs[c * 68 + r] = B[(size_t)(col0 + r) * M + k0 + c];
    }
    __syncthreads();
#pragma unroll
    for (int kk = 0; kk < 32; ++kk) {
      float4 a = *(const float4*)(As + kk * 68 + ty * 4);
      float4 b = *(const float4*)(Bs + kk * 68 + tx * 4);
      float av[4] = {a.x, a.y, a.z, a.w}, bv[4] = {b.x, b.y, b.z, b.w};
#pragma unroll
      for (int r = 0; r < 4; ++r)
#pragma unroll
        for (int c = 0; c < 4; ++c) acc[r][c] = fmaf(av[r], bv[c], acc[r][c]);
    }
    __syncthreads();
  }
#pragma unroll
  for (int r = 0; r < 4; ++r)
#pragma unroll
    for (int c = 0; c < 4; ++c) {
      float x = acc[r][c];
      unsigned short h = f2bf(x);
      size_t o = (size_t)(row0 + ty * 4 + r) * M + col0 + tx * 4 + c;
      Ch[o] = h;
      Cl[o] = f2bf(x - bf2f(h));
    }
}

// ---------------------------------------------------------------------------
// Tiled transpose + hi/lo split. rh/rl (row-major) optional.
// ---------------------------------------------------------------------------
__global__ __launch_bounds__(256) void trsplit(const float* __restrict__ src,
                                               unsigned short* rh, unsigned short* rl,
                                               unsigned short* __restrict__ th,
                                               unsigned short* __restrict__ tl) {
  __shared__ float T[64][65];
  const int i0 = blockIdx.x * 64, m0 = blockIdx.y * 64;
  const int tid = threadIdx.x;
#pragma unroll
  for (int l = 0; l < 16; ++l) {
    int idx = tid + l * 256;
    int r = idx >> 6, c = idx & 63;
    float x = src[(size_t)(i0 + r) * M + m0 + c];
    T[r][c] = x;
    if (rh != nullptr) {
      unsigned short h = f2bf(x);
      size_t o = (size_t)(i0 + r) * M + m0 + c;
      rh[o] = h;
      rl[o] = f2bf(x - bf2f(h));
    }
  }
  __syncthreads();
#pragma unroll
  for (int l = 0; l < 16; ++l) {
    int idx = tid + l * 256;
    int r = idx >> 6, c = idx & 63;  // r: m-local, c: i-local
    float x = T[c][r];
    unsigned short h = f2bf(x);
    size_t o = (size_t)(m0 + r) * N + i0 + c;
    th[o] = h;
    tl[o] = f2bf(x - bf2f(h));
  }
}

// ---------------------------------------------------------------------------
// Stats: per (i-panel 128, j-eighth 1024): corr tiles via bf16x3 MFMA,
// E = exp(corr - 96); additive row partial sums + col partial sums.
// ---------------------------------------------------------------------------
__global__ __launch_bounds__(512) void stats_mfma(
    const unsigned short* __restrict__ Aph, const unsigned short* __restrict__ Apl,
    const unsigned short* __restrict__ Vh, const unsigned short* __restrict__ Vl,
    float* __restrict__ rps, float* __restrict__ cps) {
  __shared__ unsigned short Vs[64 * 264];
  __shared__ float cred[8][64];
  const int tid = threadIdx.x;
  const int w = tid >> 6, l = tid & 63;
  const int lm = l & 15, lk = l >> 4;
  const int p = blockIdx.x, q = blockIdx.y;
  const int arow = p * 128 + w * 16 + lm;

  bf16x8 ah[8];
#pragma unroll
  for (int kk = 0; kk < 8; ++kk) ah[kk] = ld8(Aph + (size_t)arow * M + kk * 32 + lk * 8);
  const unsigned short* alp = Apl + (size_t)arow * M + lk * 8;

  float rsum[4] = {0.f, 0.f, 0.f, 0.f};

  for (int jt = 0; jt < 16; ++jt) {
    const int j0 = q * 1024 + jt * 64;
    __syncthreads();
#pragma unroll
    for (int s = 0; s < 4; ++s) {
      int slot = tid + s * 512;
      int r = slot >> 5, c = slot & 31;
      *(bf16x8*)(Vs + r * 264 + c * 8) = ld8(Vh + (size_t)(j0 + r) * M + c * 8);
    }
    __syncthreads();

    f32x4 acc[4];
#pragma unroll
    for (int js = 0; js < 4; ++js) acc[js] = f32x4{0.f, 0.f, 0.f, 0.f};
#pragma unroll
    for (int js = 0; js < 4; ++js) {
      const unsigned short* vsr = Vs + (js * 16 + lm) * 264 + lk * 8;
      const unsigned short* vlr = Vl + (size_t)(j0 + js * 16 + lm) * M + lk * 8;
#pragma unroll
      for (int kk = 0; kk < 8; ++kk) {
        bf16x8 bh = ld8(vsr + kk * 32);
        bf16x8 bl = ld8(vlr + kk * 32);
        bf16x8 al = ld8(alp + kk * 32);
        acc[js] = mfma16(ah[kk], bh, acc[js]);
        acc[js] = mfma16(ah[kk], bl, acc[js]);
        acc[js] = mfma16(al, bh, acc[js]);
      }
    }
#pragma unroll
    for (int js = 0; js < 4; ++js) {
      float e0 = __expf(acc[js][0] - SHIFT), e1 = __expf(acc[js][1] - SHIFT);
      float e2 = __expf(acc[js][2] - SHIFT), e3 = __expf(acc[js][3] - SHIFT);
      rsum[0] += e0; rsum[1] += e1; rsum[2] += e2; rsum[3] += e3;
      float c = e0 + e1 + e2 + e3;
      c += __shfl_xor(c, 16);
      c += __shfl_xor(c, 32);
      if (lk == 0) cred[w][js * 16 + lm] = c;
    }
    __syncthreads();
    if (tid < 64) {
      float c = 0.f;
#pragma unroll
      for (int ww = 0; ww < 8; ++ww) c += cred[ww][tid];
      cps[(size_t)p * N + j0 + tid] = c;
    }
  }
#pragma unroll
  for (int r = 0; r < 4; ++r) {
    float s = rsum[r];
    s += __shfl_xor(s, 1);
    s += __shfl_xor(s, 2);
    s += __shfl_xor(s, 4);
    s += __shfl_xor(s, 8);
    if (lm == 0) rps[(size_t)q * N + p * 128 + w * 16 + lk * 4 + r] = s;
  }
}

__global__ void row_inv(const float* __restrict__ rps, float* __restrict__ rinv) {
  int i = blockIdx.x * 256 + threadIdx.x;
  float s = 0.f;
#pragma unroll
  for (int q = 0; q < 8; ++q) s += rps[(size_t)q * N + i];
  rinv[i] = 1.f / s;
}
__global__ void col_inv(const float* __restrict__ cps, float* __restrict__ cinv) {
  int j = blockIdx.x * 256 + threadIdx.x;
  float s = 0.f;
  for (int p = 0; p < 64; ++p) s += cps[(size_t)p * N + j];
  cinv[j] = 1.f / s;
}

// ---------------------------------------------------------------------------
// out_audio: d_audio[i,m] = sum_j E(corr[i,j])*cinv[j] * audio[j,m]
// corr tile: A = Ap[i-panel 64] (regs), B = V[j-tile 64] (LDS hi + global lo)
// ---------------------------------------------------------------------------
__global__ __launch_bounds__(512) void out_audio_m(
    const unsigned short* __restrict__ Aph, const unsigned short* __restrict__ Apl,
    const unsigned short* __restrict__ Vh, const unsigned short* __restrict__ Vl,
    const unsigned short* __restrict__ AuTh, const unsigned short* __restrict__ AuTl,
    const float* __restrict__ cinv, float* __restrict__ out) {
  __shared__ unsigned short Vs[64 * 264];
  __shared__ unsigned short Wh[64 * 72], Wl[64 * 72];
  const int tid = threadIdx.x;
  const int w = tid >> 6, l = tid & 63;
  const int lm = l & 15, lk = l >> 4;
  const int i0 = blockIdx.x * 64;
  const int jh = blockIdx.y;  // j-quarter
  const int isub = w & 3, half = w >> 2;

  const int arow = i0 + isub * 16 + lm;
  bf16x8 ah[8];
#pragma unroll
  for (int kk = 0; kk < 8; ++kk) ah[kk] = ld8(Aph + (size_t)arow * M + kk * 32 + lk * 8);
  const unsigned short* alp = Apl + (size_t)arow * M + lk * 8;

  f32x4 dacc[8];
#pragma unroll
  for (int ms = 0; ms < 8; ++ms) dacc[ms] = f32x4{0.f, 0.f, 0.f, 0.f};
  const int m0 = half * 128;

  for (int jt = 0; jt < 32; ++jt) {
    const int j0 = jh * 2048 + jt * 64;
    __syncthreads();
#pragma unroll
    for (int s = 0; s < 4; ++s) {
      int slot = tid + s * 512;
      int r = slot >> 5, c = slot & 31;
      *(bf16x8*)(Vs + r * 264 + c * 8) = ld8(Vh + (size_t)(j0 + r) * M + c * 8);
    }
    __syncthreads();

    f32x4 cacc[2];
    cacc[0] = f32x4{0.f, 0.f, 0.f, 0.f};
    cacc[1] = f32x4{0.f, 0.f, 0.f, 0.f};
#pragma unroll
    for (int js2 = 0; js2 < 2; ++js2) {
      int js = half * 2 + js2;
      const unsigned short* vsr = Vs + (js * 16 + lm) * 264 + lk * 8;
      const unsigned short* vlr = Vl + (size_t)(j0 + js * 16 + lm) * M + lk * 8;
#pragma unroll
      for (int kk = 0; kk < 8; ++kk) {
        bf16x8 bh = ld8(vsr + kk * 32);
        bf16x8 bl = ld8(vlr + kk * 32);
        bf16x8 al = ld8(alp + kk * 32);
        cacc[js2] = mfma16(ah[kk], bh, cacc[js2]);
        cacc[js2] = mfma16(ah[kk], bl, cacc[js2]);
        cacc[js2] = mfma16(al, bh, cacc[js2]);
      }
    }
    // weights -> LDS (lane holds rows isub*16+lk*4+r, col js*16+lm)
#pragma unroll
    for (int js2 = 0; js2 < 2; ++js2) {
      int js = half * 2 + js2;
      float ci = cinv[j0 + js * 16 + lm];
#pragma unroll
      for (int r = 0; r < 4; ++r) {
        float e = __expf(cacc[js2][r] - SHIFT) * ci;
        unsigned short h = f2bf(e);
        int irow = isub * 16 + lk * 4 + r;
        Wh[irow * 72 + js * 16 + lm] = h;
        Wl[irow * 72 + js * 16 + lm] = f2bf(e - bf2f(h));
      }
    }
    __syncthreads();
    // weighted: A = W rows (isub*16+lm), B = AuT
#pragma unroll
    for (int kk = 0; kk < 2; ++kk) {
      bf16x8 wh = ld8(Wh + (isub * 16 + lm) * 72 + kk * 32 + lk * 8);
      bf16x8 wl = ld8(Wl + (isub * 16 + lm) * 72 + kk * 32 + lk * 8);
#pragma unroll
      for (int ms = 0; ms < 8; ++ms) {
        size_t bo = (size_t)(m0 + ms * 16 + lm) * N + j0 + kk * 32 + lk * 8;
        bf16x8 vh8 = ld8(AuTh + bo);
        bf16x8 vl8 = ld8(AuTl + bo);
        dacc[ms] = mfma16(wh, vh8, dacc[ms]);
        dacc[ms] = mfma16(wh, vl8, dacc[ms]);
        dacc[ms] = mfma16(wl, vh8, dacc[ms]);
      }
    }
  }
#pragma unroll
  for (int ms = 0; ms < 8; ++ms)
#pragma unroll
    for (int r = 0; r < 4; ++r) {
      int i = i0 + isub * 16 + lk * 4 + r;
      int m = m0 + ms * 16 + lm;
      atomicAdd(out + (size_t)i * (2 * M) + M + m, dacc[ms][r]);
    }
}

// ---------------------------------------------------------------------------
// out_video: d_video[i,m] = sum_j E(corr[j,i])*rinv[j] * video[j,m]
// corr tile: A = Ap[j-tile] (global), B = video[i-panel] (LDS hi, once)
// ---------------------------------------------------------------------------
__global__ __launch_bounds__(512) void out_video_m(
    const unsigned short* __restrict__ Aph, const unsigned short* __restrict__ Apl,
    const unsigned short* __restrict__ Vh, const unsigned short* __restrict__ Vl,
    const unsigned short* __restrict__ ViTh, const unsigned short* __restrict__ ViTl,
    const float* __restrict__ rinv, float* __restrict__ out) {
  __shared__ unsigned short Vs[64 * 264];
  __shared__ unsigned short Wh[64 * 72], Wl[64 * 72];
  const int tid = threadIdx.x;
  const int w = tid >> 6, l = tid & 63;
  const int lm = l & 15, lk = l >> 4;
  const int i0 = blockIdx.x * 64;
  const int jh = blockIdx.y;
  const int jsub = w & 3, half = w >> 2;

  // stage video[i-panel] hi once
#pragma unroll
  for (int s = 0; s < 4; ++s) {
    int slot = tid + s * 512;
    int r = slot >> 5, c = slot & 31;
    *(bf16x8*)(Vs + r * 264 + c * 8) = ld8(Vh + (size_t)(i0 + r) * M + c * 8);
  }
  __syncthreads();

  f32x4 dacc[8];
#pragma unroll
  for (int ms = 0; ms < 8; ++ms) dacc[ms] = f32x4{0.f, 0.f, 0.f, 0.f};
  const int m0 = half * 128;

  for (int jt = 0; jt < 32; ++jt) {
    const int j0 = jh * 2048 + jt * 64;
    // corr: A = Ap rows j, B = video rows i (LDS hi + global lo)
    f32x4 cacc[2];
    cacc[0] = f32x4{0.f, 0.f, 0.f, 0.f};
    cacc[1] = f32x4{0.f, 0.f, 0.f, 0.f};
    const int jrow = j0 + jsub * 16 + lm;
    const unsigned short* aphr = Aph + (size_t)jrow * M + lk * 8;
    const unsigned short* aplr = Apl + (size_t)jrow * M + lk * 8;
#pragma unroll
    for (int kk = 0; kk < 8; ++kk) {
      bf16x8 ahf = ld8(aphr + kk * 32);
      bf16x8 alf = ld8(aplr + kk * 32);
#pragma unroll
      for (int is2 = 0; is2 < 2; ++is2) {
        int isub = half * 2 + is2;
        bf16x8 bh = ld8(Vs + (isub * 16 + lm) * 264 + kk * 32 + lk * 8);
        bf16x8 bl = ld8(Vl + (size_t)(i0 + isub * 16 + lm) * M + kk * 32 + lk * 8);
        cacc[is2] = mfma16(ahf, bh, cacc[is2]);
        cacc[is2] = mfma16(ahf, bl, cacc[is2]);
        cacc[is2] = mfma16(alf, bh, cacc[is2]);
      }
    }
    __syncthreads();  // prior weighted reads of W done
    // weights: lane holds D[j-local = jsub*16+lk*4+r][i-local = isub*16+lm]
    float rv[4];
#pragma unroll
    for (int r = 0; r < 4; ++r) rv[r] = rinv[j0 + jsub * 16 + lk * 4 + r];
#pragma unroll
    for (int is2 = 0; is2 < 2; ++is2) {
      int isub = half * 2 + is2;
#pragma unroll
      for (int r = 0; r < 4; ++r) {
        float e = __expf(cacc[is2][r] - SHIFT) * rv[r];
        unsigned short h = f2bf(e);
        int jl = jsub * 16 + lk * 4 + r;
        Wh[(isub * 16 + lm) * 72 + jl] = h;
        Wl[(isub * 16 + lm) * 72 + jl] = f2bf(e - bf2f(h));
      }
    }
    __syncthreads();
    // weighted: A = W rows (i-local jsub*16+lm!), reuse jsub as i-sub
#pragma unroll
    for (int kk = 0; kk < 2; ++kk) {
      bf16x8 wh = ld8(Wh + (jsub * 16 + lm) * 72 + kk * 32 + lk * 8);
      bf16x8 wl = ld8(Wl + (jsub * 16 + lm) * 72 + kk * 32 + lk * 8);
#pragma unroll
      for (int ms = 0; ms < 8; ++ms) {
        size_t bo = (size_t)(m0 + ms * 16 + lm) * N + j0 + kk * 32 + lk * 8;
        bf16x8 vh8 = ld8(ViTh + bo);
        bf16x8 vl8 = ld8(ViTl + bo);
        dacc[ms] = mfma16(wh, vh8, dacc[ms]);
        dacc[ms] = mfma16(wh, vl8, dacc[ms]);
        dacc[ms] = mfma16(wl, vh8, dacc[ms]);
      }
    }
  }
#pragma unroll
  for (int ms = 0; ms < 8; ++ms)
#pragma unroll
    for (int r = 0; r < 4; ++r) {
      int i = i0 + jsub * 16 + lk * 4 + r;
      int m = m0 + ms * 16 + lm;
      atomicAdd(out + (size_t)i * (2 * M) + m, dacc[ms][r]);
    }
}

// ---------------------------------------------------------------------------
__global__ void epilogue(float* __restrict__ out, const float* __restrict__ video,
                         const float* __restrict__ audio) {
  int idx = blockIdx.x * 256 + threadIdx.x;  // over N*512/4 float4s
  int i = idx >> 7;
  int c4 = idx & 127;
  float4 o = reinterpret_cast<float4*>(out)[(size_t)i * 128 + c4];
  const float* res = (c4 < 64) ? (video + (size_t)i * M + c4 * 4)
                               : (audio + (size_t)i * M + (c4 - 64) * 4);
  float4 rv = *reinterpret_cast<const float4*>(res);
  o.x = tanhf(o.x + rv.x);
  o.y = tanhf(o.y + rv.y);
  o.z = tanhf(o.z + rv.z);
  o.w = tanhf(o.w + rv.w);
  reinterpret_cast<float4*>(out)[(size_t)i * 128 + c4] = o;
}

// ---------------------------------------------------------------------------
extern "C" void kernel_launch(void* const* d_in, const int* in_sizes, int n_in,
                              void* d_out, int out_size, void* d_ws, size_t ws_size,
                              hipStream_t stream) {
  const float* audio = (const float*)d_in[0];
  const float* video = (const float*)d_in[1];
  const float* W = (const float*)d_in[2];
  float* out = (float*)d_out;

  // workspace layout (bytes)
  const size_t nBF = (size_t)N * M * sizeof(unsigned short);  // 4 MB
  char* base = (char*)d_ws;
  unsigned short* Aph = (unsigned short*)(base);
  unsigned short* Apl = (unsigned short*)(base + nBF);
  unsigned short* Vh = (unsigned short*)(base + 2 * nBF);
  unsigned short* Vl = (unsigned short*)(base + 3 * nBF);
  unsigned short* ViTh = (unsigned short*)(base + 4 * nBF);
  unsigned short* ViTl = (unsigned short*)(base + 5 * nBF);
  unsigned short* AuTh = (unsigned short*)(base + 6 * nBF);
  unsigned short* AuTl = (unsigned short*)(base + 7 * nBF);
  float* rps = (float*)(base + 8 * nBF);              // 8*N
  float* cps = rps + 8 * (size_t)N;                   // 64*N
  float* rinv = cps + 64 * (size_t)N;                 // N
  float* cinv = rinv + N;                             // N
  const size_t need = 8 * nBF + (74 * (size_t)N) * sizeof(float);
  if (ws_size < need) return;

  zero_f32<<<dim3((N * 2 * M / 4 + 255) / 256), 256, 0, stream>>>(out, N * 2 * M / 4);
  gemm_ap<<<dim3(N / 64, M / 64), 256, 0, stream>>>(audio, W, Aph, Apl);
  trsplit<<<dim3(N / 64, M / 64), 256, 0, stream>>>(video, Vh, Vl, ViTh, ViTl);
  trsplit<<<dim3(N / 64, M / 64), 256, 0, stream>>>(audio, nullptr, nullptr, AuTh, AuTl);
  stats_mfma<<<dim3(64, 8), 512, 0, stream>>>(Aph, Apl, Vh, Vl, rps, cps);
  row_inv<<<N / 256, 256, 0, stream>>>(rps, rinv);
  col_inv<<<N / 256, 256, 0, stream>>>(cps, cinv);
  out_audio_m<<<dim3(N / 64, 4), 512, 0, stream>>>(Aph, Apl, Vh, Vl, AuTh, AuTl, cinv, out);
  out_video_m<<<dim3(N / 64, 4), 512, 0, stream>>>(Aph, Apl, Vh, Vl, ViTh, ViTl, rinv, out);
  epilogue<<<dim3(N * 2 * M / 4 / 256), 256, 0, stream>>>(out, video, audio);
}